// Round 5
// baseline (214.283 us; speedup 1.0000x reference)
//
#include <hip/hip_runtime.h>
#include <hip/hip_bf16.h>

// CTC batch cost — R4/R5: TWO-KERNEL SPLIT for per-phase rocprof attribution +
// phase-1 occupancy fix. (R5 = identical resubmit of R4; R4 bench was an
// infra acquisition timeout, no data.)
//   Kernel A (ctc_phase1): gather the 34 needed log-prob columns per (b,t)
//     into row-major tables lp[t][36] and dump to workspace. 2048 blocks x
//     128 rows, LDS 18.4KB -> 8 blocks/CU = 32 waves/CU (was 16).
//   Kernel B (ctc_scan): 1 wave per problem, 127 fwd+bwd interleaved f64
//     steps (DPP shifts, bit-identical math to the verified kernel), reading
//     rows from the L2/L3-resident workspace with one-group-ahead prefetch
//     pinned by sched_barrier(0).
// Fallback to the verified single-kernel if ws_size < 37.75 MB.
// B=1024, T=256, C=128, L=32, S=65, blank=127.

#define CTC_B 1024
#define CTC_T 256
#define CTC_C 128
#define CTC_L 32
#define CTC_BLANK 127
#define CTC_EPS 1e-7f

#define ROWS 36                      // padded row stride (dwords); 144B = 16B-aligned
#define PROB_DW (CTC_T * ROWS)       // 9216 dwords per problem
#define WS_NEED ((size_t)CTC_B * PROB_DW * 4)

#define DPP_WAVE_SHL1 0x130  // lane i <- lane i+1, lane 63 <- 0 (bound_ctrl)
#define DPP_WAVE_SHR1 0x138  // lane i <- lane i-1, lane 0  <- 0 (bound_ctrl)

__device__ __forceinline__ double bperm_f64(int addr, double v) {
    union { double d; int i[2]; } u; u.d = v;
    int x = __builtin_amdgcn_ds_bpermute(addr, u.i[0]);
    int y = __builtin_amdgcn_ds_bpermute(addr, u.i[1]);
    union { int i[2]; double d; } r; r.i[0] = x; r.i[1] = y;
    return r.d;
}

__device__ __forceinline__ double dpp_shr1_f64(double v) {
    union { double d; int i[2]; } u; u.d = v;
    int x = __builtin_amdgcn_update_dpp(0, u.i[0], DPP_WAVE_SHR1, 0xF, 0xF, true);
    int y = __builtin_amdgcn_update_dpp(0, u.i[1], DPP_WAVE_SHR1, 0xF, 0xF, true);
    union { int i[2]; double d; } r; r.i[0] = x; r.i[1] = y;
    return r.d;
}

__device__ __forceinline__ double dpp_shl1_f64(double v) {
    union { double d; int i[2]; } u; u.d = v;
    int x = __builtin_amdgcn_update_dpp(0, u.i[0], DPP_WAVE_SHL1, 0xF, 0xF, true);
    int y = __builtin_amdgcn_update_dpp(0, u.i[1], DPP_WAVE_SHL1, 0xF, 0xF, true);
    union { int i[2]; double d; } r; r.i[0] = x; r.i[1] = y;
    return r.d;
}

__device__ __forceinline__ double bcast0_f64(double v) {
    union { double d; int i[2]; } u; u.d = v;
    int x = __builtin_amdgcn_readfirstlane(u.i[0]);
    int y = __builtin_amdgcn_readfirstlane(u.i[1]);
    union { int i[2]; double d; } r; r.i[0] = x; r.i[1] = y;
    return r.d;
}

// ======================= Kernel A: table build ============================
// blk = 2*b + half; covers rows t in [half*128, half*128+128).
// 4 waves x 32 rows each. LDS 128*36*4 = 18,432B -> 8 blocks/CU, 32 waves/CU.
__global__ __launch_bounds__(256) void ctc_phase1_kernel(
    const int* __restrict__ y_true,
    const float* __restrict__ y_pred,
    float* __restrict__ ws)
{
    __shared__ float lp[128 * ROWS];

    const int blk = blockIdx.x;
    const int b = blk >> 1;
    const int half = blk & 1;
    const int tid = threadIdx.x;
    const int lane = tid & 63;
    const int wave = tid >> 6;

    const float* yp = y_pred + (size_t)b * CTC_T * CTC_C;

    int lbl = CTC_BLANK;
    if (lane < CTC_L) lbl = y_true[b * CTC_L + lane];

    const int tbase = half * 128;
    const int t0 = tbase + wave * 32;
    const int src_addr = (lbl >> 1) << 2;   // byte addr of source lane
    const bool odd = (lbl & 1) != 0;

    #pragma unroll 8
    for (int k = 0; k < 32; ++k) {
        const int t = t0 + k;
        const float2 r =
            *reinterpret_cast<const float2*>(yp + (size_t)t * CTC_C + 2 * lane);
        union { float f; int i; } c0, c1;
        c0.f = r.x; c1.f = r.y;
        int g0 = __builtin_amdgcn_ds_bpermute(src_addr, c0.i);
        int g1 = __builtin_amdgcn_ds_bpermute(src_addr, c1.i);
        union { int i; float f; } s0, s1;
        s0.i = g0; s1.i = g1;
        float p = odd ? s1.f : s0.f;
        float v = (lane == 33) ? 0.0f : (p + CTC_EPS) * 128.0f;
        // bank = (36t + lane)%32 = (4t + lane)%32 -> 2-way max (free)
        if (lane <= 33) lp[(t - tbase) * ROWS + lane] = v;
    }
    __syncthreads();

    // linear coalesced dump: 128*36 dwords = 1152 int4
    const int4* src = reinterpret_cast<const int4*>(lp);
    int4* dst = reinterpret_cast<int4*>(ws + (size_t)b * PROB_DW + (size_t)tbase * ROWS);
    #pragma unroll
    for (int i = 0; i < 5; ++i) {
        const int q = tid + i * 256;
        if (q < 1152) dst[q] = src[q];
    }
}

// ========================= Kernel B: scan =================================
// 1 wave per problem; reads row-major tables from ws (L2/L3 resident).
__global__ __launch_bounds__(64) void ctc_scan_kernel(
    const int* __restrict__ y_true,
    const float* __restrict__ ws,
    float* __restrict__ out)
{
    const int b = blockIdx.x;
    const int lane = threadIdx.x;
    const float* tab = ws + (size_t)b * PROB_DW;

    int lbl = CTC_BLANK;
    if (lane < CTC_L) lbl = y_true[b * CTC_L + lane];

    double skip = 0.0;
    if (lane >= 1 && lane < CTC_L) {
        if (y_true[b * CTC_L + lane - 1] != lbl) skip = 1.0;
    }
    double skipn = 0.0;
    if (lane <= 30) {
        if (y_true[b * CTC_L + lane + 1] != lbl) skipn = 1.0;
    } else if (lane == 32) {
        skipn = 1.0;
    }

    const int lidx = (lane < 32) ? lane : 32;
    const int pv_idx = (lane < 32) ? lane : 33;
    const int tn = (lane <= 30) ? (lane + 1)
                 : (lane == 31) ? 33
                 : (lane == 32) ? 0
                 : 32;
    const int pbi = (lane == 32) ? 33 : 32;
    const bool is32 = (lane == 32);

    double lo = 0.0, hi = 0.0;
    if (lane == 0) {
        lo = (double)tab[32];   // row 0, blank col
        hi = (double)tab[0];    // row 0, label-0 col
    }
    double a = 0.0, bb = 0.0;
    if (lane == 31) { a = 1.0; bb = 1.0; }

#define STEP(pvf, pbf, paf, pa1f, pbbf) {                       \
        double ph  = dpp_shr1_f64(hi);                          \
        double a1s = dpp_shl1_f64(a);                           \
        double a1  = is32 ? bcast0_f64(a) : a1s;                \
        double nl = (lo + ph) * (double)(pbf);                  \
        double nh = (hi + lo + skip * ph) * (double)(pvf);      \
        double v  = (double)(pa1f) * a1;                        \
        double u  = (double)(pbbf) * bb;                        \
        double nb = u + v;                                      \
        double na = fma((double)(paf), a, fma(skipn, v, u));    \
        lo = nl; hi = nh; a = na; bb = nb;                      \
    }

    // group g covers k = 4g..4g+3 (fwd t = 1+k, bwd t = 255-k).
    // 32 groups; STEPs run for k=0..126; group 31 slot 3 (k=127) feeds the
    // final backward-only step (row 128); its fwd loads are dead-but-safe.
    float cpv[4], cpb[4], cpa[4], cp1[4], cpbb[4];
    float npv[4], npb[4], npa[4], np1[4], npbb[4];

    #pragma unroll
    for (int j = 0; j < 4; ++j) {
        const float* rf = tab + (size_t)(1 + j) * ROWS;
        const float* rb = tab + (size_t)(255 - j) * ROWS;
        cpv[j] = rf[pv_idx]; cpb[j] = rf[32];
        cpa[j] = rb[lidx];   cp1[j] = rb[tn]; cpbb[j] = rb[pbi];
    }

    for (int g = 0; g < 31; ++g) {
        // issue next group's 20 loads before computing current group
        #pragma unroll
        for (int j = 0; j < 4; ++j) {
            const int kk = 4 * (g + 1) + j;
            const float* rf = tab + (size_t)(1 + kk) * ROWS;
            const float* rb = tab + (size_t)(255 - kk) * ROWS;
            npv[j] = rf[pv_idx]; npb[j] = rf[32];
            npa[j] = rb[lidx];   np1[j] = rb[tn]; npbb[j] = rb[pbi];
        }
        __builtin_amdgcn_sched_barrier(0);
        #pragma unroll
        for (int j = 0; j < 4; ++j)
            STEP(cpv[j], cpb[j], cpa[j], cp1[j], cpbb[j]);
        __builtin_amdgcn_sched_barrier(0);
        #pragma unroll
        for (int j = 0; j < 4; ++j) {
            cpv[j] = npv[j]; cpb[j] = npb[j];
            cpa[j] = npa[j]; cp1[j] = np1[j]; cpbb[j] = npbb[j];
        }
    }

    // tail: k = 124, 125, 126
    STEP(cpv[0], cpb[0], cpa[0], cp1[0], cpbb[0]);
    STEP(cpv[1], cpb[1], cpa[1], cp1[1], cpbb[1]);
    STEP(cpv[2], cpb[2], cpa[2], cp1[2], cpbb[2]);

    // final backward-only step: t = 128 (group 31 slot 3)
    {
        double a1s = dpp_shl1_f64(a);
        double a1  = is32 ? bcast0_f64(a) : a1s;
        double v  = (double)cp1[3] * a1;
        double u  = (double)cpbb[3] * bb;
        double nb = u + v;
        double na = fma((double)cpa[3], a, fma(skipn, v, u));
        a = na; bb = nb;
    }
#undef STEP

    // combine: P = sum_s alpha_127[s] * beta_127[s]
    double beA = bperm_f64(32 << 2, a);                      // all: a_32
    double beB = bperm_f64(((lane + 63) & 63) << 2, bb);     // bb_{i-1}
    double be = (lane == 0) ? beA : beB;
    double partial = (lane <= 32) ? (lo * be + hi * a) : 0.0;
    #pragma unroll
    for (int off = 32; off >= 1; off >>= 1)
        partial += __shfl_down(partial, off);
    if (lane == 0) {
        out[b] = (float)(1242.1197475634219 - log(partial)); // 256*ln(128)
    }
}

// ================== Fallback: verified single kernel ======================
#define KSTRIDE 130
#define TABSZ  (34 * KSTRIDE)

__global__ __launch_bounds__(256) void ctc_loss_kernel(
    const int* __restrict__ y_true,
    const float* __restrict__ y_pred,
    float* __restrict__ out)
{
    __shared__ float tabs[2 * TABSZ];
    float* Ftab = tabs;
    float* Btab = tabs + TABSZ;

    const int b = blockIdx.x;
    const int tid = threadIdx.x;
    const int lane = tid & 63;
    const int wave = tid >> 6;

    const float* yp = y_pred + (size_t)b * CTC_T * CTC_C;

    int lbl = CTC_BLANK;
    if (lane < CTC_L) lbl = y_true[b * CTC_L + lane];

    {
        const int t0 = wave * 64;
        const int src_addr = (lbl >> 1) << 2;
        const bool odd = (lbl & 1) != 0;
        float* tab = (wave < 2) ? Ftab : Btab;
        #pragma unroll 8
        for (int k = 0; k < 64; ++k) {
            const int t = t0 + k;
            const float2 r =
                *reinterpret_cast<const float2*>(yp + (size_t)t * CTC_C + 2 * lane);
            union { float f; int i; } c0, c1;
            c0.f = r.x; c1.f = r.y;
            int g0 = __builtin_amdgcn_ds_bpermute(src_addr, c0.i);
            int g1 = __builtin_amdgcn_ds_bpermute(src_addr, c1.i);
            union { int i; float f; } s0, s1;
            s0.i = g0; s1.i = g1;
            float p = odd ? s1.f : s0.f;
            float v = (lane == 33) ? 0.0f : (p + CTC_EPS) * 128.0f;
            const int idx = (wave < 2) ? ((t + 127) & 127) : (255 - t);
            if (lane <= 33) tab[lane * KSTRIDE + idx] = v;
        }
    }
    __syncthreads();

    if (wave != 0) return;

    double skip = 0.0;
    if (lane >= 1 && lane < CTC_L) {
        if (y_true[b * CTC_L + lane - 1] != lbl) skip = 1.0;
    }
    double skipn = 0.0;
    if (lane <= 30) {
        if (y_true[b * CTC_L + lane + 1] != lbl) skipn = 1.0;
    } else if (lane == 32) {
        skipn = 1.0;
    }

    const int lidx = (lane < 32) ? lane : 32;
    const int pv_idx = (lane < 32) ? lane : 33;
    const int tn = (lane <= 30) ? (lane + 1)
                 : (lane == 31) ? 33
                 : (lane == 32) ? 0
                 : 32;
    const int pbi = (lane == 32) ? 33 : 32;
    const bool is32 = (lane == 32);

    const float* Fpv = Ftab + pv_idx * KSTRIDE;
    const float* Fpb = Ftab + 32 * KSTRIDE;
    const float* Bpa = Btab + lidx * KSTRIDE;
    const float* Bp1 = Btab + tn * KSTRIDE;
    const float* Bpb = Btab + pbi * KSTRIDE;

    double lo = 0.0, hi = 0.0;
    if (lane == 0) {
        lo = (double)Ftab[32 * KSTRIDE + 127];
        hi = (double)Ftab[0 * KSTRIDE + 127];
    }
    double a = 0.0, bb = 0.0;
    if (lane == 31) { a = 1.0; bb = 1.0; }

#define STEP(pvf, pbf, paf, pa1f, pbbf) {                       \
        double ph  = dpp_shr1_f64(hi);                          \
        double a1s = dpp_shl1_f64(a);                           \
        double a1  = is32 ? bcast0_f64(a) : a1s;                \
        double nl = (lo + ph) * (double)(pbf);                  \
        double nh = (hi + lo + skip * ph) * (double)(pvf);      \
        double v  = (double)(pa1f) * a1;                        \
        double u  = (double)(pbbf) * bb;                        \
        double nb = u + v;                                      \
        double na = fma((double)(paf), a, fma(skipn, v, u));    \
        lo = nl; hi = nh; a = na; bb = nb;                      \
    }

    for (int k = 0; k < 127; ++k) {
        float pvf  = Fpv[k];
        float pbf  = Fpb[k];
        float paf  = Bpa[k];
        float pa1f = Bp1[k];
        float pbbf = Bpb[k];
        STEP(pvf, pbf, paf, pa1f, pbbf);
    }
    {
        double a1s = dpp_shl1_f64(a);
        double a1  = is32 ? bcast0_f64(a) : a1s;
        double v  = (double)Bp1[127] * a1;
        double u  = (double)Bpb[127] * bb;
        double nb = u + v;
        double na = fma((double)Bpa[127], a, fma(skipn, v, u));
        a = na; bb = nb;
    }
#undef STEP

    double beA = bperm_f64(32 << 2, a);
    double beB = bperm_f64(((lane + 63) & 63) << 2, bb);
    double be = (lane == 0) ? beA : beB;
    double partial = (lane <= 32) ? (lo * be + hi * a) : 0.0;
    #pragma unroll
    for (int off = 32; off >= 1; off >>= 1)
        partial += __shfl_down(partial, off);
    if (lane == 0) {
        out[b] = (float)(1242.1197475634219 - log(partial));
    }
}

extern "C" void kernel_launch(void* const* d_in, const int* in_sizes, int n_in,
                              void* d_out, int out_size, void* d_ws, size_t ws_size,
                              hipStream_t stream) {
    const int*   y_true = (const int*)d_in[0];
    const float* y_pred = (const float*)d_in[1];
    float*       out    = (float*)d_out;

    if (d_ws != nullptr && ws_size >= WS_NEED) {
        float* ws = (float*)d_ws;
        ctc_phase1_kernel<<<2 * CTC_B, 256, 0, stream>>>(y_true, y_pred, ws);
        ctc_scan_kernel<<<CTC_B, 64, 0, stream>>>(y_true, ws, out);
    } else {
        ctc_loss_kernel<<<CTC_B, 256, 0, stream>>>(y_true, y_pred, out);
    }
}

// Round 6
// 203.495 us; speedup vs baseline: 1.0530x; 1.0530x over previous
//
#include <hip/hip_runtime.h>
#include <hip/hip_bf16.h>

// CTC batch cost — R6: REVERT phase 1 to the original divergent gather
// (the 203.7-us session's code), keep phase 2 on DPP shifts (HW-verified
// in R3/R5 benches, absmax=0.0). Fused single kernel.
//
// Rationale: harness totals 203.7 (orig gather) -> 210/212/214 (bpermute
// gather variants) while every phase-2 change measured neutral. The R1
// "coalescing fix" (load->vmcnt->bpermute->lgkm->select chain per row) is
// the only change ever correlated with a delta, and in the WRONG direction.
// This round isolates gather style at the counter level: ctc_loss_kernel
// lands back in rocprof's top-5 next to the 77.0us R2 measurement.
//
// Structure (unchanged from verified baseline):
//   P = sum_s alpha_127[s] * beta_127[s], 127 fwd+bwd interleaved f64 steps.
//   Forward: lane i holds alpha[2i] (lo), alpha[2i+1] (hi).
//   Backward: lane i holds beta[2i+1] (a), beta[2i+2] (b); beta[0] @ lane32.a.
//   All boundary masking baked into per-lane LDS indices (slot 33 = 0).
// B=1024, T=256, C=128, L=32, S=65, blank=127.

#define CTC_B 1024
#define CTC_T 256
#define CTC_C 128
#define CTC_L 32
#define CTC_BLANK 127
#define CTC_EPS 1e-7f

#define RSTRIDE 34   // 32 labels + blank(32) + zero slot(33)

#define DPP_WAVE_SHL1 0x130  // lane i <- lane i+1, lane 63 <- 0 (bound_ctrl)
#define DPP_WAVE_SHR1 0x138  // lane i <- lane i-1, lane 0  <- 0 (bound_ctrl)

__device__ __forceinline__ double bperm_f64(int addr, double v) {
    union { double d; int i[2]; } u; u.d = v;
    int x = __builtin_amdgcn_ds_bpermute(addr, u.i[0]);
    int y = __builtin_amdgcn_ds_bpermute(addr, u.i[1]);
    union { int i[2]; double d; } r; r.i[0] = x; r.i[1] = y;
    return r.d;
}

// lane i <- lane i-1 (lane 0 <- 0): forward alpha[2i-1] shift.
// (Old bpermute wrap pulled lane 63's hi into lane 0 — provably always 0,
// so bound_ctrl zero-fill is identical. Verified absmax=0.0 in R3/R5.)
__device__ __forceinline__ double dpp_shr1_f64(double v) {
    union { double d; int i[2]; } u; u.d = v;
    int x = __builtin_amdgcn_update_dpp(0, u.i[0], DPP_WAVE_SHR1, 0xF, 0xF, true);
    int y = __builtin_amdgcn_update_dpp(0, u.i[1], DPP_WAVE_SHR1, 0xF, 0xF, true);
    union { int i[2]; double d; } r; r.i[0] = x; r.i[1] = y;
    return r.d;
}

// lane i <- lane i+1 (lane 63 <- 0): backward beta shift (lane 63 dead-zero).
__device__ __forceinline__ double dpp_shl1_f64(double v) {
    union { double d; int i[2]; } u; u.d = v;
    int x = __builtin_amdgcn_update_dpp(0, u.i[0], DPP_WAVE_SHL1, 0xF, 0xF, true);
    int y = __builtin_amdgcn_update_dpp(0, u.i[1], DPP_WAVE_SHL1, 0xF, 0xF, true);
    union { int i[2]; double d; } r; r.i[0] = x; r.i[1] = y;
    return r.d;
}

// broadcast lane 0's value (wave 0 fully active here)
__device__ __forceinline__ double bcast0_f64(double v) {
    union { double d; int i[2]; } u; u.d = v;
    int x = __builtin_amdgcn_readfirstlane(u.i[0]);
    int y = __builtin_amdgcn_readfirstlane(u.i[1]);
    union { int i[2]; double d; } r; r.i[0] = x; r.i[1] = y;
    return r.d;
}

__global__ __launch_bounds__(256) void ctc_loss_kernel(
    const int* __restrict__ y_true,   // [B, L] int32
    const float* __restrict__ y_pred, // [B, T, C] float32
    float* __restrict__ out)          // [B, 1] float32
{
    __shared__ float lp[CTC_T * RSTRIDE];  // 34.8 KB -> 4 blocks/CU

    const int b = blockIdx.x;
    const int tid = threadIdx.x;
    const int lane = tid & 63;
    const int wave = tid >> 6;

    const float* yp = y_pred + (size_t)b * CTC_T * CTC_C;

    // per-lane gather label: lanes 0..31 -> y_true, others -> blank
    int lbl = CTC_BLANK;
    if (lane < CTC_L) lbl = y_true[b * CTC_L + lane];

    // ---- phase 1 (ORIGINAL divergent gather): wave w fills t in
    // [w*64, w*64+64); slot 33 = 0. Lane i loads column lbl_i directly —
    // 34 unique addresses per row, absorbed by L1/L2/L3; no DS dependency
    // chain. This is the 203.7-session code path.
    {
        const int t0 = wave * 64;
        #pragma unroll 8
        for (int k = 0; k < 64; ++k) {
            int t = t0 + k;
            float p = yp[t * CTC_C + lbl];
            float v = (lane == 33) ? 0.0f : (p + CTC_EPS) * 128.0f;
            if (lane <= 33) lp[t * RSTRIDE + lane] = v;
        }
    }
    __syncthreads();

    if (wave != 0) return;

    // ---- per-lane constants ----
    // forward skip: state 2i+1 may come from 2i-1 iff y[i] != y[i-1]
    double skip = 0.0;
    if (lane >= 1 && lane < CTC_L) {
        if (y_true[b * CTC_L + lane - 1] != lbl) skip = 1.0;
    }
    // backward skip-in: state 2i+3 reachable from 2i+1 iff y[i+1] != y[i]
    double skipn = 0.0;
    if (lane <= 30) {
        if (y_true[b * CTC_L + lane + 1] != lbl) skipn = 1.0;
    } else if (lane == 32) {
        skipn = 1.0;   // reuse v-term as the 0 -> 1 transition
    }

    const int lidx = (lane < 32) ? lane : 32;          // own label slot
    const int pv_idx = (lane < 32) ? lane : 33;        // fwd label (0 if dead)
    const int tn = (lane <= 30) ? (lane + 1)
                 : (lane == 31) ? 33                    // state 65: killed
                 : (lane == 32) ? 0                     // beta[0] uses p[1]
                 : 32;                                  // dead: harmless
    const int pbi = (lane == 32) ? 33 : 32;            // bwd blank (0 @ 32)
    const bool is32 = (lane == 32);

    // ---- init ----
    double lo = 0.0, hi = 0.0;          // alpha
    if (lane == 0) {
        lo = (double)lp[32];            // alpha[0] = blank @ t=0
        hi = (double)lp[0];             // alpha[1] = label0 @ t=0
    }
    double a = 0.0, bb = 0.0;           // beta (a = odd 2i+1, bb = even 2i+2)
    if (lane == 31) { a = 1.0; bb = 1.0; }   // beta_255[63] = beta_255[64] = 1

    // ---- 127 interleaved iterations: fwd t=1..127, bwd t=255..129 ----
    for (int k = 0; k < 127; ++k) {
        const int tf = 1 + k;
        const int tb = 255 - k;
        float pvf  = lp[tf * RSTRIDE + pv_idx];
        float pbf  = lp[tf * RSTRIDE + 32];
        float paf  = lp[tb * RSTRIDE + lidx];
        float pa1f = lp[tb * RSTRIDE + tn];
        float pbbf = lp[tb * RSTRIDE + pbi];

        // register-only cross-lane shifts
        double ph  = dpp_shr1_f64(hi);             // alpha[2i-1]; lane0 <- 0
        double a1s = dpp_shl1_f64(a);              // a from lane+1
        double a1  = is32 ? bcast0_f64(a) : a1s;   // lane32 <- beta[1]

        // forward
        double nl = (lo + ph) * (double)pbf;
        double nh = (hi + lo + skip * ph) * (double)pvf;
        // backward
        double v  = (double)pa1f * a1;
        double u  = (double)pbbf * bb;
        double nb = u + v;
        double na = fma((double)paf, a, fma(skipn, v, u));

        lo = nl; hi = nh; a = na; bb = nb;
    }

    // ---- final backward-only step: tb = 128 -> beta_127 ----
    {
        const int tb = 128;
        float paf  = lp[tb * RSTRIDE + lidx];
        float pa1f = lp[tb * RSTRIDE + tn];
        float pbbf = lp[tb * RSTRIDE + pbi];
        double a1s = dpp_shl1_f64(a);
        double a1  = is32 ? bcast0_f64(a) : a1s;
        double v  = (double)pa1f * a1;
        double u  = (double)pbbf * bb;
        double nb = u + v;
        double na = fma((double)paf, a, fma(skipn, v, u));
        a = na; bb = nb;
    }

    // ---- combine: P = sum_s alpha_127[s] * beta_127[s] ----
    // beta[2i]: i=0 -> a_32 (beta[0]); i>=1 -> bb_{i-1}
    double beA = bperm_f64(32 << 2, a);                      // all: a_32
    double beB = bperm_f64(((lane + 63) & 63) << 2, bb);     // bb_{i-1}
    double be = (lane == 0) ? beA : beB;
    double partial = (lane <= 32) ? (lo * be + hi * a) : 0.0;
    #pragma unroll
    for (int off = 32; off >= 1; off >>= 1)
        partial += __shfl_down(partial, off);
    if (lane == 0) {
        out[b] = (float)(1242.1197475634219 - log(partial)); // 256*ln(128)
    }
}

extern "C" void kernel_launch(void* const* d_in, const int* in_sizes, int n_in,
                              void* d_out, int out_size, void* d_ws, size_t ws_size,
                              hipStream_t stream) {
    const int*   y_true = (const int*)d_in[0];
    const float* y_pred = (const float*)d_in[1];
    float*       out    = (float*)d_out;

    ctc_loss_kernel<<<CTC_B, 256, 0, stream>>>(y_true, y_pred, out);
}

// Round 7
// 193.198 us; speedup vs baseline: 1.1091x; 1.0533x over previous
//
#include <hip/hip_runtime.h>
#include <hip/hip_bf16.h>

// CTC batch cost — R7: FULLY FUSED single-wave scan. Phase 1 (LDS table
// build, 4 waves, barrier) is DELETED. Each block = one 64-lane wave that
// loads its 5 per-iteration operands directly from global memory, software-
// pipelined one 8-iteration group ahead (global loads are vmcnt-counted, no
// barriers anywhere -> the compiler preserves the pipeline).
//
// Evidence: R6 kernel ~70.5us = phase1 ~40 + phase2 ~30 (cross-validated by
// R5 split and occupancy decomposition); kernel insensitive to cache state;
// all phase-2-internal variants neutral. Phase 1 + staging + barrier is pure
// overhead if the scan feeds itself; fused floor = BW/latency of reading the
// needed rows (~128MB line-granularity, ~half L3-resident).
//
// Math is bit-identical to the verified kernel (absmax=0.0): same f32
// (p+EPS)*128 pre-scale, same f64 op order; LDS zero-slot -> cndmask,
// LDS broadcast-slot -> readlane.
// B=1024, T=256, C=128, L=32, S=65, blank=127.

#define CTC_B 1024
#define CTC_T 256
#define CTC_C 128
#define CTC_L 32
#define CTC_BLANK 127
#define CTC_EPS 1e-7f

#define DPP_WAVE_SHL1 0x130  // lane i <- lane i+1, lane 63 <- 0 (bound_ctrl)
#define DPP_WAVE_SHR1 0x138  // lane i <- lane i-1, lane 0  <- 0 (bound_ctrl)

__device__ __forceinline__ double bperm_f64(int addr, double v) {
    union { double d; int i[2]; } u; u.d = v;
    int x = __builtin_amdgcn_ds_bpermute(addr, u.i[0]);
    int y = __builtin_amdgcn_ds_bpermute(addr, u.i[1]);
    union { int i[2]; double d; } r; r.i[0] = x; r.i[1] = y;
    return r.d;
}

__device__ __forceinline__ double dpp_shr1_f64(double v) {
    union { double d; int i[2]; } u; u.d = v;
    int x = __builtin_amdgcn_update_dpp(0, u.i[0], DPP_WAVE_SHR1, 0xF, 0xF, true);
    int y = __builtin_amdgcn_update_dpp(0, u.i[1], DPP_WAVE_SHR1, 0xF, 0xF, true);
    union { int i[2]; double d; } r; r.i[0] = x; r.i[1] = y;
    return r.d;
}

__device__ __forceinline__ double dpp_shl1_f64(double v) {
    union { double d; int i[2]; } u; u.d = v;
    int x = __builtin_amdgcn_update_dpp(0, u.i[0], DPP_WAVE_SHL1, 0xF, 0xF, true);
    int y = __builtin_amdgcn_update_dpp(0, u.i[1], DPP_WAVE_SHL1, 0xF, 0xF, true);
    union { int i[2]; double d; } r; r.i[0] = x; r.i[1] = y;
    return r.d;
}

__device__ __forceinline__ int dpp_shl1_i32(int v) {
    return __builtin_amdgcn_update_dpp(0, v, DPP_WAVE_SHL1, 0xF, 0xF, true);
}

__device__ __forceinline__ double bcast0_f64(double v) {
    union { double d; int i[2]; } u; u.d = v;
    int x = __builtin_amdgcn_readfirstlane(u.i[0]);
    int y = __builtin_amdgcn_readfirstlane(u.i[1]);
    union { int i[2]; double d; } r; r.i[0] = x; r.i[1] = y;
    return r.d;
}

__global__ __launch_bounds__(64) void ctc_loss_kernel(
    const int* __restrict__ y_true,   // [B, L] int32
    const float* __restrict__ y_pred, // [B, T, C] float32
    float* __restrict__ out)          // [B, 1] float32
{
    const int b = blockIdx.x;
    const int lane = threadIdx.x;

    const float* yp = y_pred + (size_t)b * CTC_T * CTC_C;

    // per-lane label: lanes 0..31 -> y_true, others -> blank
    int lbl = CTC_BLANK;
    if (lane < CTC_L) lbl = y_true[b * CTC_L + lane];

    // ---- per-lane transition constants (identical to verified kernel) ----
    double skip = 0.0;
    if (lane >= 1 && lane < CTC_L) {
        if (y_true[b * CTC_L + lane - 1] != lbl) skip = 1.0;
    }
    double skipn = 0.0;
    if (lane <= 30) {
        if (y_true[b * CTC_L + lane + 1] != lbl) skipn = 1.0;
    } else if (lane == 32) {
        skipn = 1.0;   // reuse v-term as the 0 -> 1 transition
    }
    const bool is32 = (lane == 32);

    // ---- per-lane gather columns (fixed across all rows) ----
    // col_a: own slot column  = label (lanes<32) else blank. Serves BOTH the
    //        forward pv/pb load (row tf) and the backward pa/pbb load (row tb).
    // col_n: next-slot column = label_{lane+1} (<=30), lbl_0 (lane 32, for
    //        beta[0] <- p[1]), blank elsewhere (dead/masked lanes).
    const int col_a = (lane < 32) ? lbl : CTC_BLANK;
    const int lbl_next = dpp_shl1_i32(lbl);                 // lane+1's label
    const int lbl0 = __builtin_amdgcn_readfirstlane(lbl);   // label_0
    const int col_n = (lane <= 31) ? lbl_next
                    : (lane == 32) ? lbl0
                    : CTC_BLANK;

    // ---- init (t=0 row) ----
    double lo = 0.0, hi = 0.0;
    if (lane == 0) {
        lo = (double)((yp[CTC_BLANK] + CTC_EPS) * 128.0f);  // alpha[0]: blank
        hi = (double)((yp[lbl] + CTC_EPS) * 128.0f);        // alpha[1]: label0
    }
    double a = 0.0, bb = 0.0;
    if (lane == 31) { a = 1.0; bb = 1.0; }  // beta_255[63] = beta_255[64] = 1

    // ---- full STEP (bit-identical f64 order to verified kernel) ----
#define STEPK(Ltf, Lta, Ltn) {                                      \
        float vtf = ((Ltf) + CTC_EPS) * 128.0f;                     \
        float vta = ((Lta) + CTC_EPS) * 128.0f;                     \
        float vtn = ((Ltn) + CTC_EPS) * 128.0f;                     \
        float pbf = __int_as_float(                                 \
            __builtin_amdgcn_readlane(__float_as_int(vtf), 32));    \
        float pbbb = __int_as_float(                                \
            __builtin_amdgcn_readlane(__float_as_int(vta), 63));    \
        float pvf  = (lane < 32) ? vtf : 0.0f;                      \
        float paf  = vta;                                           \
        float pa1f = (lane == 31) ? 0.0f : vtn;                     \
        float pbbf = is32 ? 0.0f : pbbb;                            \
        double ph  = dpp_shr1_f64(hi);                              \
        double a1s = dpp_shl1_f64(a);                               \
        double a1  = is32 ? bcast0_f64(a) : a1s;                    \
        double nl = (lo + ph) * (double)pbf;                        \
        double nh = (hi + lo + skip * ph) * (double)pvf;            \
        double v  = (double)pa1f * a1;                              \
        double u  = (double)pbbf * bb;                              \
        double nb = u + v;                                          \
        double na = fma((double)paf, a, fma(skipn, v, u));          \
        lo = nl; hi = nh; a = na; bb = nb;                          \
    }

    // group of 8 slots; slot s of group g is k = 8g+s; fwd row 1+k, bwd 255-k.
#define LOADG(dtf, dta, dtn, g) {                                   \
        _Pragma("unroll")                                           \
        for (int s = 0; s < 8; ++s) {                               \
            const int k = 8 * (g) + s;                              \
            const float* rf = yp + (size_t)(1 + k) * CTC_C;         \
            const float* rb = yp + (size_t)(255 - k) * CTC_C;       \
            dtf[s] = rf[col_a];                                     \
            dta[s] = rb[col_a];                                     \
            dtn[s] = rb[col_n];                                     \
        }                                                           \
    }

    float ctf[8], cta[8], ctn[8];
    float ntf[8], nta[8], ntn[8];

    // prologue: group 0 (k = 0..7)
    LOADG(ctf, cta, ctn, 0);

    // groups 0..14: compute current, prefetch next. (k runs 0..119 here.)
    for (int g = 0; g < 15; ++g) {
        LOADG(ntf, nta, ntn, g + 1);
        __builtin_amdgcn_sched_barrier(0);
        #pragma unroll
        for (int s = 0; s < 8; ++s)
            STEPK(ctf[s], cta[s], ctn[s]);
        __builtin_amdgcn_sched_barrier(0);
        #pragma unroll
        for (int s = 0; s < 8; ++s) {
            ctf[s] = ntf[s]; cta[s] = nta[s]; ctn[s] = ntn[s];
        }
    }

    // group 15: slots 0..6 are full steps (k = 120..126); slot 7 (k = 127)
    // feeds the final backward-only step (row tb = 255-127 = 128).
    #pragma unroll
    for (int s = 0; s < 7; ++s)
        STEPK(ctf[s], cta[s], ctn[s]);

    {   // final backward-only step: row 128 -> beta_127
        float vta = (cta[7] + CTC_EPS) * 128.0f;
        float vtn = (ctn[7] + CTC_EPS) * 128.0f;
        float pbbb = __int_as_float(
            __builtin_amdgcn_readlane(__float_as_int(vta), 63));
        float paf  = vta;
        float pa1f = (lane == 31) ? 0.0f : vtn;
        float pbbf = is32 ? 0.0f : pbbb;
        double a1s = dpp_shl1_f64(a);
        double a1  = is32 ? bcast0_f64(a) : a1s;
        double v  = (double)pa1f * a1;
        double u  = (double)pbbf * bb;
        double nb = u + v;
        double na = fma((double)paf, a, fma(skipn, v, u));
        a = na; bb = nb;
    }
#undef STEPK
#undef LOADG

    // ---- combine: P = sum_s alpha_127[s] * beta_127[s] ----
    // beta[2i]: i=0 -> a_32 (beta[0]); i>=1 -> bb_{i-1}
    double beA = bperm_f64(32 << 2, a);                      // all: a_32
    double beB = bperm_f64(((lane + 63) & 63) << 2, bb);     // bb_{i-1}
    double be = (lane == 0) ? beA : beB;
    double partial = (lane <= 32) ? (lo * be + hi * a) : 0.0;
    #pragma unroll
    for (int off = 32; off >= 1; off >>= 1)
        partial += __shfl_down(partial, off);
    if (lane == 0) {
        out[b] = (float)(1242.1197475634219 - log(partial)); // 256*ln(128)
    }
}

extern "C" void kernel_launch(void* const* d_in, const int* in_sizes, int n_in,
                              void* d_out, int out_size, void* d_ws, size_t ws_size,
                              hipStream_t stream) {
    const int*   y_true = (const int*)d_in[0];
    const float* y_pred = (const float*)d_in[1];
    float*       out    = (float*)d_out;

    ctc_loss_kernel<<<CTC_B, 64, 0, stream>>>(y_true, y_pred, out);
}